// Round 1
// baseline (553.958 us; speedup 1.0000x reference)
//
#include <hip/hip_runtime.h>
#include <hip/hip_bf16.h>
#include <stdint.h>
#include <stddef.h>

typedef __bf16 bf16;
typedef __bf16 bf16x8 __attribute__((ext_vector_type(8)));
typedef float  f32x4  __attribute__((ext_vector_type(4)));

static constexpr int M = 8192, N = 4096, K = 4096;
static constexpr int BM = 128, BN = 128, BK = 32;

// ---------------- preprocessing ----------------

// cast x (fp32) -> bf16, 8 elems/thread
__global__ void cast_x_kernel(const float* __restrict__ x, bf16* __restrict__ xb) {
    int i = blockIdx.x * blockDim.x + threadIdx.x;
    const float4* x4 = (const float4*)x;
    float4 a = x4[2 * i], b = x4[2 * i + 1];
    bf16x8 o;
    o[0] = (bf16)a.x; o[1] = (bf16)a.y; o[2] = (bf16)a.z; o[3] = (bf16)a.w;
    o[4] = (bf16)b.x; o[5] = (bf16)b.y; o[6] = (bf16)b.z; o[7] = (bf16)b.w;
    *(bf16x8*)(xb + 8 * (size_t)i) = o;
}

// w (fp32) -> sign(w) in bf16 (+1 / -1 / 0 exact), 8 elems/thread
__global__ void binarize_w_kernel(const float* __restrict__ w, bf16* __restrict__ wb) {
    int i = blockIdx.x * blockDim.x + threadIdx.x;
    const float4* w4 = (const float4*)w;
    float4 a = w4[2 * i], b = w4[2 * i + 1];
    float v[8] = {a.x, a.y, a.z, a.w, b.x, b.y, b.z, b.w};
    bf16x8 o;
#pragma unroll
    for (int j = 0; j < 8; ++j)
        o[j] = (bf16)((v[j] > 0.f) ? 1.f : ((v[j] < 0.f) ? -1.f : 0.f));
    *(bf16x8*)(wb + 8 * (size_t)i) = o;
}

// ---------------- GEMM ----------------
// C[M,N] = Xb[M,K] @ Wb[N,K]^T + bias      (B^T layout, m97 structure)
// 128x128 block tile, BK=32, 4 waves in 2x2 (64x64 per wave),
// mfma_f32_16x16x32_bf16, global_load_lds width=16, XOR-swizzled LDS granules.

__device__ __forceinline__ void async_copy16(const bf16* g, bf16* l) {
    __builtin_amdgcn_global_load_lds(
        (const __attribute__((address_space(1))) void*)g,
        (__attribute__((address_space(3))) void*)l,
        16, 0, 0);
}

__global__ __launch_bounds__(256) void gemm_bin(const bf16* __restrict__ A,   // [M,K]
                                                const bf16* __restrict__ B,   // [N,K]
                                                const float* __restrict__ bias,
                                                float* __restrict__ C) {      // [M,N]
    __shared__ __align__(16) bf16 As[BM * BK];  // 8 KB, swizzled 16B granules
    __shared__ __align__(16) bf16 Bs[BN * BK];  // 8 KB

    const int tid  = threadIdx.x;
    const int lane = tid & 63;
    const int wave = tid >> 6;
    const int m0 = blockIdx.y * BM;
    const int n0 = blockIdx.x * BN;

    const int wr = wave >> 1, wc = wave & 1;  // 2x2 wave grid
    const int q  = lane >> 4;                 // quad (0..3) -> k-offset q*8
    const int lr = lane & 15;                 // row/col within 16

    f32x4 acc[4][4];
#pragma unroll
    for (int i = 0; i < 4; ++i)
#pragma unroll
        for (int j = 0; j < 4; ++j) acc[i][j] = (f32x4)0.f;

    // staging granule decomposition: slot s in [0,512), 16 B each
    // s -> r = s>>2 (tile row), c = s&3 (16B seg); stored seg cg = c ^ ((r>>1)&3)
    int s0 = tid;          // issue 0
    int s1 = tid + 256;    // issue 1
    int r0 = s0 >> 2, cg0 = (s0 & 3) ^ ((r0 >> 1) & 3);
    int r1 = s1 >> 2, cg1 = (s1 & 3) ^ ((r1 >> 1) & 3);
    const bf16* gA0 = A + (size_t)(m0 + r0) * K + cg0 * 8;
    const bf16* gA1 = A + (size_t)(m0 + r1) * K + cg1 * 8;
    const bf16* gB0 = B + (size_t)(n0 + r0) * K + cg0 * 8;
    const bf16* gB1 = B + (size_t)(n0 + r1) * K + cg1 * 8;

    // fragment LDS slots (swizzled), in bf16 elements
    int aoff[4], boff[4];
#pragma unroll
    for (int mi = 0; mi < 4; ++mi) {
        int r = wr * 64 + mi * 16 + lr;
        aoff[mi] = (r * 4 + (q ^ ((r >> 1) & 3))) * 8;
        int rb = wc * 64 + mi * 16 + lr;
        boff[mi] = (rb * 4 + (q ^ ((rb >> 1) & 3))) * 8;
    }

    for (int kt = 0; kt < K / BK; ++kt) {
        const int kofs = kt * BK;
        async_copy16(gA0 + kofs, As + s0 * 8);
        async_copy16(gA1 + kofs, As + s1 * 8);
        async_copy16(gB0 + kofs, Bs + s0 * 8);
        async_copy16(gB1 + kofs, Bs + s1 * 8);
        __syncthreads();  // drains vmcnt -> LDS populated

        bf16x8 af[4], bfr[4];
#pragma unroll
        for (int mi = 0; mi < 4; ++mi) af[mi]  = *(const bf16x8*)(As + aoff[mi]);
#pragma unroll
        for (int ni = 0; ni < 4; ++ni) bfr[ni] = *(const bf16x8*)(Bs + boff[ni]);

#pragma unroll
        for (int mi = 0; mi < 4; ++mi)
#pragma unroll
            for (int ni = 0; ni < 4; ++ni)
                acc[mi][ni] = __builtin_amdgcn_mfma_f32_16x16x32_bf16(
                    af[mi], bfr[ni], acc[mi][ni], 0, 0, 0);
        __syncthreads();  // before overwriting LDS next iter
    }

    // epilogue: C/D layout col = lane&15, row = (lane>>4)*4 + reg
#pragma unroll
    for (int ni = 0; ni < 4; ++ni) {
        int col = n0 + wc * 64 + ni * 16 + lr;
        float bv = bias[col];
#pragma unroll
        for (int mi = 0; mi < 4; ++mi) {
            int row0 = m0 + wr * 64 + mi * 16 + q * 4;
#pragma unroll
            for (int i = 0; i < 4; ++i)
                C[(size_t)(row0 + i) * N + col] = acc[mi][ni][i] + bv;
        }
    }
}

// ---------------- launch ----------------

extern "C" void kernel_launch(void* const* d_in, const int* in_sizes, int n_in,
                              void* d_out, int out_size, void* d_ws, size_t ws_size,
                              hipStream_t stream) {
    const float* x    = (const float*)d_in[0];  // [8192, 4096]
    const float* w    = (const float*)d_in[1];  // [4096, 4096]
    const float* bias = (const float*)d_in[2];  // [4096]
    float* out        = (float*)d_out;          // [8192, 4096]

    bf16* xb = (bf16*)d_ws;                 // 64 MB
    bf16* wb = xb + (size_t)M * K;          // +32 MB  (needs ws_size >= 96 MB)

    cast_x_kernel<<<(M * K) / (8 * 256), 256, 0, stream>>>(x, xb);
    binarize_w_kernel<<<(N * K) / (8 * 256), 256, 0, stream>>>(w, wb);

    dim3 grid(N / BN, M / BM);  // (32, 64)
    gemm_bin<<<grid, 256, 0, stream>>>(xb, wb, bias, out);
}

// Round 2
// 483.425 us; speedup vs baseline: 1.1459x; 1.1459x over previous
//
#include <hip/hip_runtime.h>
#include <hip/hip_bf16.h>
#include <stdint.h>
#include <stddef.h>

typedef int    i32x4 __attribute__((ext_vector_type(4)));

static constexpr int M = 8192, N = 4096, K = 4096;
static constexpr int BM = 128, BN = 128, BK = 64;   // BK=64: one i8 MFMA k-step

// ---------------- preprocessing ----------------

// Pass 1: absmax(x) via grid-stride + wave reduce + one atomicMax/wave.
__global__ void absmax_kernel(const float* __restrict__ x, unsigned* __restrict__ out, int n4) {
    int stride = gridDim.x * blockDim.x;
    float m = 0.f;
    const float4* x4 = (const float4*)x;
    for (int i = blockIdx.x * blockDim.x + threadIdx.x; i < n4; i += stride) {
        float4 v = x4[i];
        m = fmaxf(m, fmaxf(fmaxf(fabsf(v.x), fabsf(v.y)), fmaxf(fabsf(v.z), fabsf(v.w))));
    }
#pragma unroll
    for (int off = 32; off; off >>= 1) m = fmaxf(m, __shfl_down(m, off, 64));
    if ((threadIdx.x & 63) == 0) atomicMax(out, __float_as_uint(m));  // all vals >= 0: uint order == float order
}

// Pass 2: quantize x -> i8 with s = 127/absmax, 16 elems/thread
__global__ void quant_x_kernel(const float* __restrict__ x, int8_t* __restrict__ xq,
                               const unsigned* __restrict__ amax_bits) {
    const float s = 127.0f / __uint_as_float(*amax_bits);
    int i = blockIdx.x * blockDim.x + threadIdx.x;
    const float4* x4 = (const float4*)x;
    int8_t o[16];
#pragma unroll
    for (int v = 0; v < 4; ++v) {
        float4 a = x4[4 * (size_t)i + v];
        o[4 * v + 0] = (int8_t)__float2int_rn(a.x * s);
        o[4 * v + 1] = (int8_t)__float2int_rn(a.y * s);
        o[4 * v + 2] = (int8_t)__float2int_rn(a.z * s);
        o[4 * v + 3] = (int8_t)__float2int_rn(a.w * s);
    }
    *(int4*)(xq + 16 * (size_t)i) = *(const int4*)o;
}

// w (fp32) -> sign(w) in i8, 16 elems/thread
__global__ void binarize_w_kernel(const float* __restrict__ w, int8_t* __restrict__ wq) {
    int i = blockIdx.x * blockDim.x + threadIdx.x;
    const float4* w4 = (const float4*)w;
    int8_t o[16];
#pragma unroll
    for (int v = 0; v < 4; ++v) {
        float4 a = w4[4 * (size_t)i + v];
        float vv[4] = {a.x, a.y, a.z, a.w};
#pragma unroll
        for (int j = 0; j < 4; ++j)
            o[4 * v + j] = (vv[j] > 0.f) ? (int8_t)1 : ((vv[j] < 0.f) ? (int8_t)-1 : (int8_t)0);
    }
    *(int4*)(wq + 16 * (size_t)i) = *(const int4*)o;
}

// ---------------- GEMM ----------------
// C[M,N] = (Xq[M,K] @ Wq[N,K]^T) * (absmax/127) + bias
// 128x128 tile, BK=64, 4 waves 2x2 (64x64 each), mfma_i32_16x16x64_i8,
// global_load_lds width=16, XOR-swizzled 16B granules (rows are 64B, as before).

__device__ __forceinline__ void async_copy16(const int8_t* g, int8_t* l) {
    __builtin_amdgcn_global_load_lds(
        (const __attribute__((address_space(1))) void*)g,
        (__attribute__((address_space(3))) void*)l,
        16, 0, 0);
}

__global__ __launch_bounds__(256) void gemm_i8(const int8_t* __restrict__ A,   // [M,K]
                                               const int8_t* __restrict__ B,   // [N,K]
                                               const float* __restrict__ bias,
                                               const unsigned* __restrict__ amax_bits,
                                               float* __restrict__ C) {        // [M,N]
    __shared__ __align__(16) int8_t As[BM * BK];  // 8 KB
    __shared__ __align__(16) int8_t Bs[BN * BK];  // 8 KB

    const int tid  = threadIdx.x;
    const int lane = tid & 63;
    const int wave = tid >> 6;
    const int m0 = blockIdx.y * BM;
    const int n0 = blockIdx.x * BN;

    const int wr = wave >> 1, wc = wave & 1;
    const int q  = lane >> 4;   // quad -> k-offset q*16
    const int lr = lane & 15;

    i32x4 acc[4][4];
#pragma unroll
    for (int i = 0; i < 4; ++i)
#pragma unroll
        for (int j = 0; j < 4; ++j) acc[i][j] = (i32x4)0;

    // staging: 512 granules of 16B per tile; slot s -> row r = s>>2, seg c = s&3,
    // stored at seg cg = c ^ ((r>>1)&3)   (same scheme that measured 0 conflicts)
    int s0 = tid, s1 = tid + 256;
    int r0 = s0 >> 2, cg0 = (s0 & 3) ^ ((r0 >> 1) & 3);
    int r1 = s1 >> 2, cg1 = (s1 & 3) ^ ((r1 >> 1) & 3);
    const int8_t* gA0 = A + (size_t)(m0 + r0) * K + cg0 * 16;
    const int8_t* gA1 = A + (size_t)(m0 + r1) * K + cg1 * 16;
    const int8_t* gB0 = B + (size_t)(n0 + r0) * K + cg0 * 16;
    const int8_t* gB1 = B + (size_t)(n0 + r1) * K + cg1 * 16;

    // fragment LDS offsets (bytes == i8 elements), 16B per lane
    int aoff[4], boff[4];
#pragma unroll
    for (int mi = 0; mi < 4; ++mi) {
        int r  = wr * 64 + mi * 16 + lr;
        aoff[mi] = (r * 4 + (q ^ ((r >> 1) & 3))) * 16;
        int rb = wc * 64 + mi * 16 + lr;
        boff[mi] = (rb * 4 + (q ^ ((rb >> 1) & 3))) * 16;
    }

    for (int kt = 0; kt < K / BK; ++kt) {   // 64 iterations
        const int kofs = kt * BK;
        async_copy16(gA0 + kofs, As + s0 * 16);
        async_copy16(gA1 + kofs, As + s1 * 16);
        async_copy16(gB0 + kofs, Bs + s0 * 16);
        async_copy16(gB1 + kofs, Bs + s1 * 16);
        __syncthreads();

        i32x4 af[4], bfr[4];
#pragma unroll
        for (int mi = 0; mi < 4; ++mi) af[mi]  = *(const i32x4*)(As + aoff[mi]);
#pragma unroll
        for (int ni = 0; ni < 4; ++ni) bfr[ni] = *(const i32x4*)(Bs + boff[ni]);

#pragma unroll
        for (int mi = 0; mi < 4; ++mi)
#pragma unroll
            for (int ni = 0; ni < 4; ++ni)
                acc[mi][ni] = __builtin_amdgcn_mfma_i32_16x16x64_i8(
                    af[mi], bfr[ni], acc[mi][ni], 0, 0, 0);
        __syncthreads();
    }

    // epilogue: C/D layout col = lane&15, row = (lane>>4)*4 + reg; dequant + bias
    const float inv_s = __uint_as_float(*amax_bits) * (1.0f / 127.0f);
#pragma unroll
    for (int ni = 0; ni < 4; ++ni) {
        int col = n0 + wc * 64 + ni * 16 + lr;
        float bv = bias[col];
#pragma unroll
        for (int mi = 0; mi < 4; ++mi) {
            int row0 = m0 + wr * 64 + mi * 16 + q * 4;
#pragma unroll
            for (int i = 0; i < 4; ++i)
                C[(size_t)(row0 + i) * N + col] = (float)acc[mi][ni][i] * inv_s + bv;
        }
    }
}

// ---------------- launch ----------------

extern "C" void kernel_launch(void* const* d_in, const int* in_sizes, int n_in,
                              void* d_out, int out_size, void* d_ws, size_t ws_size,
                              hipStream_t stream) {
    const float* x    = (const float*)d_in[0];  // [8192, 4096]
    const float* w    = (const float*)d_in[1];  // [4096, 4096]
    const float* bias = (const float*)d_in[2];  // [4096]
    float* out        = (float*)d_out;          // [8192, 4096]

    unsigned* amax = (unsigned*)d_ws;                       // 4 B scale slot
    int8_t* xq = (int8_t*)d_ws + 256;                       // 32 MB
    int8_t* wq = xq + (size_t)M * K;                        // 16 MB

    hipMemsetAsync(amax, 0, sizeof(unsigned), stream);      // ws is poisoned 0xAA
    absmax_kernel<<<1024, 256, 0, stream>>>(x, amax, (M * K) / 4);
    quant_x_kernel<<<(M * K) / (16 * 256), 256, 0, stream>>>(x, xq, amax);
    binarize_w_kernel<<<(N * K) / (16 * 256), 256, 0, stream>>>(w, wq);

    dim3 grid(N / BN, M / BM);  // (32, 64)
    gemm_i8<<<grid, 256, 0, stream>>>(xq, wq, bias, amax, out);
}

// Round 3
// 412.030 us; speedup vs baseline: 1.3445x; 1.1733x over previous
//
#include <hip/hip_runtime.h>
#include <stdint.h>
#include <stddef.h>

typedef int i32x4 __attribute__((ext_vector_type(4)));

static constexpr int M = 8192, N = 4096, K = 4096;
static constexpr int BM = 128, BN = 128, BK = 128;  // BK=128: 32 MFMA per barrier-pair

// ---------------- preprocessing ----------------

// One block per row: lane-contiguous float4 reads, block absmax reduce,
// quantize the registers we already hold, lane-contiguous dword stores.
// scales[row] = amax/127 (the dequant factor).
__global__ __launch_bounds__(256) void quant_rows(const float* __restrict__ x,
                                                  int8_t* __restrict__ xq,
                                                  float* __restrict__ scales) {
    const int row = blockIdx.x;
    const int tid = threadIdx.x;
    const float4* xr = (const float4*)(x + (size_t)row * K);  // 1024 float4/row

    float4 v[4];
    float m = 0.f;
#pragma unroll
    for (int k = 0; k < 4; ++k) {
        v[k] = xr[k * 256 + tid];  // lane-contiguous 16B/lane
        m = fmaxf(m, fmaxf(fmaxf(fabsf(v[k].x), fabsf(v[k].y)),
                           fmaxf(fabsf(v[k].z), fabsf(v[k].w))));
    }
#pragma unroll
    for (int off = 32; off; off >>= 1) m = fmaxf(m, __shfl_down(m, off, 64));

    __shared__ float wm[4];
    if ((tid & 63) == 0) wm[tid >> 6] = m;
    __syncthreads();
    const float amax = fmaxf(fmaxf(fmaxf(wm[0], wm[1]), fmaxf(wm[2], wm[3])), 1e-20f);
    const float s = 127.0f / amax;
    if (tid == 0) scales[row] = amax * (1.0f / 127.0f);

    int8_t* xo = xq + (size_t)row * K;
#pragma unroll
    for (int k = 0; k < 4; ++k) {
        int8_t o[4] = {(int8_t)__float2int_rn(v[k].x * s),
                       (int8_t)__float2int_rn(v[k].y * s),
                       (int8_t)__float2int_rn(v[k].z * s),
                       (int8_t)__float2int_rn(v[k].w * s)};
        *(int*)(xo + (k * 256 + tid) * 4) = *(const int*)o;  // lane-contiguous dwords
    }
}

// w (fp32) -> sign(w) in i8. One float4 per thread, lane-contiguous in and out.
__global__ __launch_bounds__(256) void binarize_w_kernel(const float* __restrict__ w,
                                                         int8_t* __restrict__ wq) {
    const size_t i = (size_t)blockIdx.x * 256 + threadIdx.x;
    float4 a = ((const float4*)w)[i];
    float vv[4] = {a.x, a.y, a.z, a.w};
    int8_t o[4];
#pragma unroll
    for (int j = 0; j < 4; ++j)
        o[j] = (vv[j] > 0.f) ? (int8_t)1 : ((vv[j] < 0.f) ? (int8_t)-1 : (int8_t)0);
    *(int*)(wq + 4 * i) = *(const int*)o;
}

// ---------------- GEMM ----------------
// C[M,N] = (Xq[M,K] @ Wq[N,K]^T) * scales[row] + bias[col]
// 128x128x128 tile, 4 waves 2x2 (64x64 each), mfma_i32_16x16x64_i8 x2 k-steps,
// global_load_lds width=16, XOR swizzle: granule (r, c) stored at c ^ (r&7).
// Fragment bank-group = (ks*4+q) ^ (r&7): 8 lanes/group per ds_read_b128 -> conflict-free.

__device__ __forceinline__ void async_copy16(const int8_t* g, int8_t* l) {
    __builtin_amdgcn_global_load_lds(
        (const __attribute__((address_space(1))) void*)g,
        (__attribute__((address_space(3))) void*)l,
        16, 0, 0);
}

__global__ __launch_bounds__(256) void gemm_i8(const int8_t* __restrict__ A,   // [M,K]
                                               const int8_t* __restrict__ B,   // [N,K]
                                               const float* __restrict__ bias,
                                               const float* __restrict__ scales,
                                               float* __restrict__ C) {        // [M,N]
    __shared__ __align__(16) int8_t As[BM * BK];  // 16 KB
    __shared__ __align__(16) int8_t Bs[BN * BK];  // 16 KB

    const int tid  = threadIdx.x;
    const int lane = tid & 63;
    const int wave = tid >> 6;
    const int m0 = blockIdx.y * BM;
    const int n0 = blockIdx.x * BN;

    const int wr = wave >> 1, wc = wave & 1;
    const int q  = lane >> 4;   // quad -> k-offset q*16 within a 64-wide k-step
    const int lr = lane & 15;

    i32x4 acc[4][4];
#pragma unroll
    for (int i = 0; i < 4; ++i)
#pragma unroll
        for (int j = 0; j < 4; ++j) acc[i][j] = (i32x4)0;

    // staging: 1024 granules of 16B per matrix; slot s -> row r = s>>3, seg c = s&7,
    // source seg c_src = c ^ (r&7), LDS dest = s*16 (wave-uniform base + lane*16).
    const int8_t* gA[4];
    const int8_t* gB[4];
#pragma unroll
    for (int j = 0; j < 4; ++j) {
        int s = tid + 256 * j;
        int r = s >> 3, c = s & 7;
        int cs = c ^ (r & 7);
        gA[j] = A + (size_t)(m0 + r) * K + cs * 16;
        gB[j] = B + (size_t)(n0 + r) * K + cs * 16;
    }

    // fragment LDS offsets (ks=0); ks=1 is aoff ^ 64 (granule bit2 == addr bit6)
    int aoff[4], boff[4];
#pragma unroll
    for (int mi = 0; mi < 4; ++mi) {
        int r  = wr * 64 + mi * 16 + lr;
        aoff[mi] = (r * 8 + (q ^ (r & 7))) * 16;
        int rb = wc * 64 + mi * 16 + lr;
        boff[mi] = (rb * 8 + (q ^ (rb & 7))) * 16;
    }

    for (int kt = 0; kt < K / BK; ++kt) {   // 32 iterations
        const int kofs = kt * BK;
#pragma unroll
        for (int j = 0; j < 4; ++j) async_copy16(gA[j] + kofs, As + (tid + 256 * j) * 16);
#pragma unroll
        for (int j = 0; j < 4; ++j) async_copy16(gB[j] + kofs, Bs + (tid + 256 * j) * 16);
        __syncthreads();

#pragma unroll
        for (int ks = 0; ks < 2; ++ks) {
            const int kx = ks << 6;
            i32x4 af[4], bfr[4];
#pragma unroll
            for (int mi = 0; mi < 4; ++mi) af[mi]  = *(const i32x4*)(As + (aoff[mi] ^ kx));
#pragma unroll
            for (int ni = 0; ni < 4; ++ni) bfr[ni] = *(const i32x4*)(Bs + (boff[ni] ^ kx));
#pragma unroll
            for (int mi = 0; mi < 4; ++mi)
#pragma unroll
                for (int ni = 0; ni < 4; ++ni)
                    acc[mi][ni] = __builtin_amdgcn_mfma_i32_16x16x64_i8(
                        af[mi], bfr[ni], acc[mi][ni], 0, 0, 0);
        }
        __syncthreads();
    }

    // epilogue: C/D layout col = lane&15, row = (lane>>4)*4 + reg; per-row dequant + bias
    float srow[4][4];
#pragma unroll
    for (int mi = 0; mi < 4; ++mi) {
        int row0 = m0 + wr * 64 + mi * 16 + q * 4;
#pragma unroll
        for (int i = 0; i < 4; ++i) srow[mi][i] = scales[row0 + i];
    }
#pragma unroll
    for (int ni = 0; ni < 4; ++ni) {
        int col = n0 + wc * 64 + ni * 16 + lr;
        float bv = bias[col];
#pragma unroll
        for (int mi = 0; mi < 4; ++mi) {
            int row0 = m0 + wr * 64 + mi * 16 + q * 4;
#pragma unroll
            for (int i = 0; i < 4; ++i)
                C[(size_t)(row0 + i) * N + col] = (float)acc[mi][ni][i] * srow[mi][i] + bv;
        }
    }
}

// ---------------- launch ----------------

extern "C" void kernel_launch(void* const* d_in, const int* in_sizes, int n_in,
                              void* d_out, int out_size, void* d_ws, size_t ws_size,
                              hipStream_t stream) {
    const float* x    = (const float*)d_in[0];  // [8192, 4096]
    const float* w    = (const float*)d_in[1];  // [4096, 4096]
    const float* bias = (const float*)d_in[2];  // [4096]
    float* out        = (float*)d_out;          // [8192, 4096]

    float* scales = (float*)d_ws;                       // 32 KB (8192 f32)
    int8_t* xq = (int8_t*)d_ws + 32768;                 // 32 MB
    int8_t* wq = xq + (size_t)M * K;                    // 16 MB

    quant_rows<<<M, 256, 0, stream>>>(x, xq, scales);                       // 8192 blocks
    binarize_w_kernel<<<(N * K / 4) / 256, 256, 0, stream>>>(w, wq);        // 16384 blocks

    dim3 grid(N / BN, M / BM);  // (32, 64)
    gemm_i8<<<grid, 256, 0, stream>>>(xq, wq, bias, scales, out);
}